// Round 3
// baseline (654.619 us; speedup 1.0000x reference)
//
#include <hip/hip_runtime.h>
#include <hip/hip_bf16.h>

#define NREF 131072
#define NALT 32768
#define BSEG 4096
#define D 128
#define F 512
#define H 256
#define EPS 1e-5f

typedef short short8 __attribute__((ext_vector_type(8)));
typedef float f32x4 __attribute__((ext_vector_type(4)));

// LDS union views (row strides):
//  A1 tile (ys):  bf16, stride 136  (64 rows) -- dead after a1 fragment loads
//  z2/A2 tile:    bf16, stride 264  (64 rows)
//  C f32 staging: f32,  stride 132  (64 rows) -- overlays z2/A2 rows byte-exactly
#define YS_STRIDE 136
#define ZS_STRIDE 264
#define CS_STRIDE 132

__device__ __forceinline__ float selu_f(float z) {
    const float sc = 1.0507009873554805f;
    const float al = 1.6732632423543772f;
    return z > 0.f ? sc * z : sc * al * (__expf(z) - 1.f);
}

// ---- weight packing: fp32 KxN -> bf16 MFMA B-fragment layout (16x16x32) ----
// frag index ((nt*KT + kt)*64 + lane)*8 + j  <->  B[kt*32 + (lane>>4)*8 + j][nt*16 + (lane&15)]
__device__ __forceinline__ void pack_one(const float* __restrict__ w, __bf16* __restrict__ wp,
                                         int KT, int N, int bi, int tid) {
    int idx = bi * 256 + tid;
    int j = idx & 7;
    int l = (idx >> 3) & 63;
    int t = idx >> 9;
    int kt = t % KT;
    int nt = t / KT;
    int k = kt * 32 + ((l >> 4) << 3) + j;
    int n = (nt << 4) + (l & 15);
    wp[idx] = (__bf16)w[k * N + n];
}

__global__ void pack_all(const float* w1r, const float* w1a, const float* w2r, const float* w2a,
                         __bf16* p1r, __bf16* p1a, __bf16* p2r, __bf16* p2a) {
    int b = blockIdx.x;
    if (b < 256)      pack_one(w1r, p1r, 4, F, b, threadIdx.x);
    else if (b < 512) pack_one(w1a, p1a, 4, F, b - 256, threadIdx.x);
    else if (b < 640) pack_one(w2r, p2r, 8, D, b - 512, threadIdx.x);
    else              pack_one(w2a, p2a, 8, D, b - 640, threadIdx.x);
}

// ---- load 64 rows of x, LayerNorm1, write bf16 A-operand tile (own-wave rows) ----
__device__ __forceinline__ void stage_ln1(const float* __restrict__ x, size_t row0, int tid,
                                          const float* __restrict__ n1w,
                                          const float* __restrict__ n1b,
                                          __bf16* __restrict__ u) {
    int r = tid >> 2, g = tid & 3;
    const float* xp = x + (row0 + r) * D + g * 32;
    float v[32];
#pragma unroll
    for (int i = 0; i < 8; ++i) {
        float4 t = reinterpret_cast<const float4*>(xp)[i];
        v[i*4] = t.x; v[i*4+1] = t.y; v[i*4+2] = t.z; v[i*4+3] = t.w;
    }
    float s = 0.f, ss = 0.f;
#pragma unroll
    for (int i = 0; i < 32; ++i) { s += v[i]; ss += v[i] * v[i]; }
    s += __shfl_xor(s, 1); ss += __shfl_xor(ss, 1);
    s += __shfl_xor(s, 2); ss += __shfl_xor(ss, 2);
    float mean = s * (1.f/128.f);
    float var = ss * (1.f/128.f) - mean * mean;
    float rs = rsqrtf(var + EPS);
    __attribute__((aligned(16))) __bf16 yv[32];
#pragma unroll
    for (int i = 0; i < 32; ++i) {
        int col = g*32 + i;
        yv[i] = (__bf16)((v[i] - mean) * rs * n1w[col] + n1b[col]);
    }
#pragma unroll
    for (int j = 0; j < 4; ++j)
        *reinterpret_cast<short8*>(&u[r*YS_STRIDE + g*32 + j*8]) =
            *reinterpret_cast<const short8*>(&yv[j*8]);
}

struct SideP1 {
    const float* x; const int* seg; const __bf16* w1p; const float* b1;
    float* seg_sum; float* seg_cnt;
};

struct SideP2 {
    const float* x; const int* seg; const __bf16* w1p; const float* b1;
    const __bf16* w2p; const float* b2; const float* alpha; const float* G;
    float* out;
};

// ---- Pass 1: LN1 -> z2-half GEMM1 -> SELU -> (reg) LN2 stats -> segment sums ----
__global__ __launch_bounds__(256, 4)
void pass1_kernel(SideP1 ref, SideP1 alt, int nref_blocks,
                  const float* __restrict__ n1w, const float* __restrict__ n1b,
                  const float* __restrict__ n2w, const float* __restrict__ n2b) {
    __shared__ __align__(16) __bf16 u[64 * ZS_STRIDE];
    __shared__ int seg_s[64];
    __shared__ float stat_s[64][2];

    SideP1 S;
    size_t row0;
    if (blockIdx.x < (unsigned)nref_blocks) { S = ref; row0 = (size_t)blockIdx.x * 64; }
    else { S = alt; row0 = (size_t)(blockIdx.x - nref_blocks) * 64; }

    const int tid = threadIdx.x;
    if (tid < 64) {
        int sg = S.seg[row0 + tid];
        seg_s[tid] = sg;
        atomicAdd(&S.seg_cnt[sg], 1.f);   // HW resolves ~2 distinct addrs per wave
    }
    stage_ln1(S.x, row0, tid, n1w, n1b, u);

    const int w = tid >> 6, lane = tid & 63;
    const int lcol = lane & 15, quad = lane >> 4;
    const int mrow = w*16 + lcol;

    short8 a1[4];   // own-wave ys rows -> no barrier needed before these loads
#pragma unroll
    for (int kt = 0; kt < 4; ++kt)
        a1[kt] = *reinterpret_cast<const short8*>(&u[mrow*YS_STRIDE + kt*32 + quad*8]);
    __syncthreads();  // all a1 loaded; ys region may now be overwritten as z2 tile

    float s4[4] = {0,0,0,0}, ss4[4] = {0,0,0,0};
#pragma unroll
    for (int nt = 0; nt < 16; ++nt) {
        int nt_g = 16 + nt;  // z2 columns of F
        f32x4 acc = {0.f,0.f,0.f,0.f};
#pragma unroll
        for (int kt = 0; kt < 4; ++kt) {
            short8 b = *reinterpret_cast<const short8*>(S.w1p + ((size_t)(nt_g*4 + kt)*64 + lane)*8);
            acc = __builtin_amdgcn_mfma_f32_16x16x32_bf16(a1[kt], b, acc, 0, 0, 0);
        }
        int col = nt*16 + lcol;          // H-space column
        float bb = S.b1[256 + col];
#pragma unroll
        for (int reg = 0; reg < 4; ++reg) {
            float z = selu_f(acc[reg] + bb);
            s4[reg] += z; ss4[reg] += z * z;
            u[(w*16 + quad*4 + reg)*ZS_STRIDE + col] = (__bf16)z;
        }
    }
#pragma unroll
    for (int reg = 0; reg < 4; ++reg) {
#pragma unroll
        for (int d = 1; d < 16; d <<= 1) {
            s4[reg]  += __shfl_xor(s4[reg], d);
            ss4[reg] += __shfl_xor(ss4[reg], d);
        }
    }
    if (lcol == 0) {
#pragma unroll
        for (int reg = 0; reg < 4; ++reg) {
            float mean = s4[reg] * (1.f/256.f);
            float var  = ss4[reg] * (1.f/256.f) - mean * mean;
            int row = w*16 + quad*4 + reg;
            stat_s[row][0] = mean;
            stat_s[row][1] = rsqrtf(var + EPS);
        }
    }
    // wave-local: segment sums over this wave's 16 rows; lane <-> column (4 passes)
#pragma unroll
    for (int p = 0; p < 4; ++p) {
        int col = p*64 + lane;
        float nw = n2w[col], nb = n2b[col];
        int scur = seg_s[w*16];
        float run = 0.f;
#pragma unroll
        for (int r16 = 0; r16 < 16; ++r16) {
            int row = w*16 + r16;
            int sg = seg_s[row];
            if (sg != scur) {
                atomicAdd(&S.seg_sum[(size_t)scur * H + col], run);
                run = 0.f; scur = sg;
            }
            run += ((float)u[row*ZS_STRIDE + col] - stat_s[row][0]) * stat_s[row][1] * nw + nb;
        }
        atomicAdd(&S.seg_sum[(size_t)scur * H + col], run);
    }
}

// ---- per-segment gate offsets ----
__global__ void mf_kernel(const float* __restrict__ sum_r, const float* __restrict__ cnt_r,
                          const float* __restrict__ sum_a, const float* __restrict__ cnt_a,
                          const float* __restrict__ regz, const float* __restrict__ reg_w_pre,
                          const float* __restrict__ beta_ref, const float* __restrict__ beta_alt,
                          const float* __restrict__ gamma,
                          float* __restrict__ G_ref, float* __restrict__ G_alt) {
    int s = blockIdx.x, c = threadIdx.x;
    size_t i = (size_t)s * H + c;
    float rw = __expf(reg_w_pre[0]) + 0.25f;
    float mfr = (sum_r[i] + rw * regz[c]) / (cnt_r[s] + rw);
    float mfa = sum_a[i] / fmaxf(cnt_a[s], 1.f);
    G_ref[i] = beta_ref[0] * mfr;
    G_alt[i] = beta_alt[0] * mfa + gamma[0] * mfr;
}

// ---- Pass 2: LN1 -> GEMM1(z2) -> stats -> GEMM1(z1)+gate -> GEMM2 -> +x+b2 ----
__global__ __launch_bounds__(256, 4)
void pass2_kernel(SideP2 ref, SideP2 alt, int nref_blocks,
                  const float* __restrict__ n1w, const float* __restrict__ n1b,
                  const float* __restrict__ n2w, const float* __restrict__ n2b) {
    __shared__ __align__(16) __bf16 u[64 * ZS_STRIDE];
    __shared__ int seg_s[64];
    __shared__ float n2w_s[H], n2b_s[H];

    SideP2 S;
    size_t row0;
    if (blockIdx.x < (unsigned)nref_blocks) { S = ref; row0 = (size_t)blockIdx.x * 64; }
    else { S = alt; row0 = (size_t)(blockIdx.x - nref_blocks) * 64; }

    const int tid = threadIdx.x;
    n2w_s[tid] = n2w[tid]; n2b_s[tid] = n2b[tid];
    if (tid < 64) seg_s[tid] = S.seg[row0 + tid];
    stage_ln1(S.x, row0, tid, n1w, n1b, u);

    const int w = tid >> 6, lane = tid & 63;
    const int lcol = lane & 15, quad = lane >> 4;
    const int mrow = w*16 + lcol;

    short8 a1[4];   // own-wave ys rows
#pragma unroll
    for (int kt = 0; kt < 4; ++kt)
        a1[kt] = *reinterpret_cast<const short8*>(&u[mrow*YS_STRIDE + kt*32 + quad*8]);
    __syncthreads();  // all a1 loaded; u may now be reused as z2/A2 tile

    // z2 half of GEMM1 + SELU + in-register LN2 partials
    float s4[4] = {0,0,0,0}, ss4[4] = {0,0,0,0};
#pragma unroll
    for (int nt = 0; nt < 16; ++nt) {
        int nt_g = 16 + nt;
        f32x4 acc = {0.f,0.f,0.f,0.f};
#pragma unroll
        for (int kt = 0; kt < 4; ++kt) {
            short8 b = *reinterpret_cast<const short8*>(S.w1p + ((size_t)(nt_g*4 + kt)*64 + lane)*8);
            acc = __builtin_amdgcn_mfma_f32_16x16x32_bf16(a1[kt], b, acc, 0, 0, 0);
        }
        int col = nt*16 + lcol;
        float bb = S.b1[256 + col];
#pragma unroll
        for (int reg = 0; reg < 4; ++reg) {
            float z = selu_f(acc[reg] + bb);
            s4[reg] += z; ss4[reg] += z * z;
            u[(w*16 + quad*4 + reg)*ZS_STRIDE + col] = (__bf16)z;
        }
    }
    float mean[4], rsg[4];
#pragma unroll
    for (int reg = 0; reg < 4; ++reg) {
#pragma unroll
        for (int d = 1; d < 16; d <<= 1) {
            s4[reg]  += __shfl_xor(s4[reg], d);
            ss4[reg] += __shfl_xor(ss4[reg], d);
        }
        mean[reg] = s4[reg] * (1.f/256.f);
        float var = ss4[reg] * (1.f/256.f) - mean[reg]*mean[reg];
        rsg[reg] = rsqrtf(var + EPS);
    }

    float alpha = S.alpha[0];
    int segb[4];
#pragma unroll
    for (int reg = 0; reg < 4; ++reg)
        segb[reg] = seg_s[w*16 + quad*4 + reg] * H;

    // z1 half of GEMM1 + SELU + gate; overwrite tile with A2 = z1*gate (same lane/addr)
#pragma unroll
    for (int nt = 0; nt < 16; ++nt) {
        f32x4 acc = {0.f,0.f,0.f,0.f};
#pragma unroll
        for (int kt = 0; kt < 4; ++kt) {
            short8 b = *reinterpret_cast<const short8*>(S.w1p + ((size_t)(nt*4 + kt)*64 + lane)*8);
            acc = __builtin_amdgcn_mfma_f32_16x16x32_bf16(a1[kt], b, acc, 0, 0, 0);
        }
        int col = nt*16 + lcol;
        float bb = S.b1[col];
        float nw = n2w_s[col], nb = n2b_s[col];
#pragma unroll
        for (int reg = 0; reg < 4; ++reg) {
            int row = w*16 + quad*4 + reg;
            float z1 = selu_f(acc[reg] + bb);
            float z2 = (float)u[row*ZS_STRIDE + col];
            float z2n = (z2 - mean[reg]) * rsg[reg] * nw + nb;
            float gate = z2n * alpha + 1.f + S.G[segb[reg] + col];
            u[row*ZS_STRIDE + col] = (__bf16)(z1 * gate);
        }
    }

    // GEMM2: (64x256)@(256x128) + b2 -> C staged in LDS (f32, own-wave rows)
    short8 a2[8];
#pragma unroll
    for (int kt = 0; kt < 8; ++kt)
        a2[kt] = *reinterpret_cast<const short8*>(&u[mrow*ZS_STRIDE + kt*32 + quad*8]);
    float* cf = reinterpret_cast<float*>(u);
#pragma unroll
    for (int nt = 0; nt < 8; ++nt) {
        f32x4 acc = {0.f,0.f,0.f,0.f};
#pragma unroll
        for (int kt = 0; kt < 8; ++kt) {
            short8 b = *reinterpret_cast<const short8*>(S.w2p + ((size_t)(nt*8 + kt)*64 + lane)*8);
            acc = __builtin_amdgcn_mfma_f32_16x16x32_bf16(a2[kt], b, acc, 0, 0, 0);
        }
        int col = nt*16 + lcol;
        float bb = S.b2[col];
#pragma unroll
        for (int reg = 0; reg < 4; ++reg)
            cf[(w*16 + quad*4 + reg)*CS_STRIDE + col] = acc[reg] + bb;
    }
    __syncthreads();

    // fully-coalesced residual add + store: wave writes 4KB contiguous per instr
#pragma unroll
    for (int i = 0; i < 8; ++i) {
        int idx = i*1024 + tid*4;
        int r = idx >> 7, c = idx & 127;
        float4 res = *reinterpret_cast<const float4*>(S.x + row0*D + idx);
        float4 o;
        o.x = cf[r*CS_STRIDE + c + 0] + res.x;
        o.y = cf[r*CS_STRIDE + c + 1] + res.y;
        o.z = cf[r*CS_STRIDE + c + 2] + res.z;
        o.w = cf[r*CS_STRIDE + c + 3] + res.w;
        *reinterpret_cast<float4*>(S.out + row0*D + idx) = o;
    }
}

extern "C" void kernel_launch(void* const* d_in, const int* in_sizes, int n_in,
                              void* d_out, int out_size, void* d_ws, size_t ws_size,
                              hipStream_t stream) {
    const float* ref_flat = (const float*)d_in[0];
    const float* alt_flat = (const float*)d_in[1];
    const int*   ref_seg  = (const int*)d_in[2];
    const int*   alt_seg  = (const int*)d_in[3];
    const float* norm1_w  = (const float*)d_in[4];
    const float* norm1_b  = (const float*)d_in[5];
    const float* w1_ref   = (const float*)d_in[6];
    const float* b1_ref   = (const float*)d_in[7];
    const float* w1_alt   = (const float*)d_in[8];
    const float* b1_alt   = (const float*)d_in[9];
    const float* norm2_w  = (const float*)d_in[10];
    const float* norm2_b  = (const float*)d_in[11];
    const float* alpha_ref = (const float*)d_in[12];
    const float* alpha_alt = (const float*)d_in[13];
    const float* beta_ref  = (const float*)d_in[14];
    const float* beta_alt  = (const float*)d_in[15];
    const float* gamma     = (const float*)d_in[16];
    const float* ref_regularizer = (const float*)d_in[17];
    const float* reg_w_pre = (const float*)d_in[18];
    const float* w2_ref   = (const float*)d_in[19];
    const float* b2_ref   = (const float*)d_in[20];
    const float* w2_alt   = (const float*)d_in[21];
    const float* b2_alt   = (const float*)d_in[22];

    char* ws = (char*)d_ws;
    float* sum_r = (float*)(ws);                      // 4 MB
    float* sum_a = (float*)(ws + 4194304);            // 4 MB
    float* cnt_r = (float*)(ws + 8388608);            // 16 KB
    float* cnt_a = (float*)(ws + 8404992);            // 16 KB
    float* G_ref = (float*)(ws + 8421376);            // 4 MB
    float* G_alt = (float*)(ws + 12615680);           // 4 MB
    __bf16* w1p_r = (__bf16*)(ws + 16809984);         // 128 KB
    __bf16* w1p_a = (__bf16*)(ws + 16941056);         // 128 KB
    __bf16* w2p_r = (__bf16*)(ws + 17072128);         // 64 KB
    __bf16* w2p_a = (__bf16*)(ws + 17137664);         // 64 KB

    hipMemsetAsync(d_ws, 0, 8421376, stream);  // zero sums + counts (atomic targets)

    pack_all<<<768, 256, 0, stream>>>(w1_ref, w1_alt, w2_ref, w2_alt, w1p_r, w1p_a, w2p_r, w2p_a);

    SideP1 p1r = { ref_flat, ref_seg, w1p_r, b1_ref, sum_r, cnt_r };
    SideP1 p1a = { alt_flat, alt_seg, w1p_a, b1_alt, sum_a, cnt_a };
    pass1_kernel<<<NREF/64 + NALT/64, 256, 0, stream>>>(p1r, p1a, NREF/64,
                                                        norm1_w, norm1_b, norm2_w, norm2_b);

    mf_kernel<<<BSEG, 256, 0, stream>>>(sum_r, cnt_r, sum_a, cnt_a, ref_regularizer, reg_w_pre,
                                        beta_ref, beta_alt, gamma, G_ref, G_alt);

    SideP2 p2r = { ref_flat, ref_seg, w1p_r, b1_ref, w2p_r, b2_ref, alpha_ref, G_ref,
                   (float*)d_out };
    SideP2 p2a = { alt_flat, alt_seg, w1p_a, b1_alt, w2p_a, b2_alt, alpha_alt, G_alt,
                   (float*)d_out + (size_t)NREF * D };
    pass2_kernel<<<NREF/64 + NALT/64, 256, 0, stream>>>(p2r, p2a, NREF/64,
                                                        norm1_w, norm1_b, norm2_w, norm2_b);
}

// Round 4
// 479.347 us; speedup vs baseline: 1.3656x; 1.3656x over previous
//
#include <hip/hip_runtime.h>
#include <hip/hip_bf16.h>

#define NREF 131072
#define NALT 32768
#define BSEG 4096
#define D 128
#define F 512
#define H 256
#define EPS 1e-5f

typedef short short8 __attribute__((ext_vector_type(8)));
typedef float f32x4 __attribute__((ext_vector_type(4)));

// LDS union views (row strides):
//  A1 tile (ys):  bf16, stride 136  (64 rows) -- dead after a1 fragment loads
//  z2/A2 tile:    bf16, stride 264  (64 rows)
//  C f32 staging: f32,  stride 132  (64 rows) -- overlays z2/A2 rows byte-exactly
#define YS_STRIDE 136
#define ZS_STRIDE 264
#define CS_STRIDE 132

__device__ __forceinline__ float selu_f(float z) {
    const float sc = 1.0507009873554805f;
    const float al = 1.6732632423543772f;
    return z > 0.f ? sc * z : sc * al * (__expf(z) - 1.f);
}

// ---- weight packing: fp32 KxN -> bf16 MFMA B-fragment layout (16x16x32) ----
// frag index ((nt*KT + kt)*64 + lane)*8 + j  <->  B[kt*32 + (lane>>4)*8 + j][nt*16 + (lane&15)]
__device__ __forceinline__ void pack_one(const float* __restrict__ w, __bf16* __restrict__ wp,
                                         int KT, int N, int bi, int tid) {
    int idx = bi * 256 + tid;
    int j = idx & 7;
    int l = (idx >> 3) & 63;
    int t = idx >> 9;
    int kt = t % KT;
    int nt = t / KT;
    int k = kt * 32 + ((l >> 4) << 3) + j;
    int n = (nt << 4) + (l & 15);
    wp[idx] = (__bf16)w[k * N + n];
}

__global__ void pack_all(const float* w1r, const float* w1a, const float* w2r, const float* w2a,
                         __bf16* p1r, __bf16* p1a, __bf16* p2r, __bf16* p2a) {
    int b = blockIdx.x;
    if (b < 256)      pack_one(w1r, p1r, 4, F, b, threadIdx.x);
    else if (b < 512) pack_one(w1a, p1a, 4, F, b - 256, threadIdx.x);
    else if (b < 640) pack_one(w2r, p2r, 8, D, b - 512, threadIdx.x);
    else              pack_one(w2a, p2a, 8, D, b - 640, threadIdx.x);
}

// ---- load 64 rows of x, LayerNorm1, write bf16 A-operand tile (own-wave rows) ----
__device__ __forceinline__ void stage_ln1(const float* __restrict__ x, size_t row0, int tid,
                                          const float* __restrict__ n1w,
                                          const float* __restrict__ n1b,
                                          __bf16* __restrict__ u) {
    int r = tid >> 2, g = tid & 3;
    const float* xp = x + (row0 + r) * D + g * 32;
    float v[32];
#pragma unroll
    for (int i = 0; i < 8; ++i) {
        float4 t = reinterpret_cast<const float4*>(xp)[i];
        v[i*4] = t.x; v[i*4+1] = t.y; v[i*4+2] = t.z; v[i*4+3] = t.w;
    }
    float s = 0.f, ss = 0.f;
#pragma unroll
    for (int i = 0; i < 32; ++i) { s += v[i]; ss += v[i] * v[i]; }
    s += __shfl_xor(s, 1); ss += __shfl_xor(ss, 1);
    s += __shfl_xor(s, 2); ss += __shfl_xor(ss, 2);
    float mean = s * (1.f/128.f);
    float var = ss * (1.f/128.f) - mean * mean;
    float rs = rsqrtf(var + EPS);
    __attribute__((aligned(16))) __bf16 yv[32];
#pragma unroll
    for (int i = 0; i < 32; ++i) {
        int col = g*32 + i;
        yv[i] = (__bf16)((v[i] - mean) * rs * n1w[col] + n1b[col]);
    }
#pragma unroll
    for (int j = 0; j < 4; ++j)
        *reinterpret_cast<short8*>(&u[r*YS_STRIDE + g*32 + j*8]) =
            *reinterpret_cast<const short8*>(&yv[j*8]);
}

struct SideP1 {
    const float* x; const int* seg; const __bf16* w1p; const float* b1;
    float* seg_sum; float* seg_cnt;
};

struct SideP2 {
    const float* x; const int* seg; const __bf16* w1p; const float* b1;
    const __bf16* w2p; const float* b2; const float* alpha; const float* G;
    float* out;
};

// ---- Pass 1: LN1 -> z2-half GEMM1 -> SELU -> (reg) LN2 stats -> segment sums ----
__global__ __launch_bounds__(256, 2)
void pass1_kernel(SideP1 ref, SideP1 alt, int nref_blocks,
                  const float* __restrict__ n1w, const float* __restrict__ n1b,
                  const float* __restrict__ n2w, const float* __restrict__ n2b) {
    __shared__ __align__(16) __bf16 u[64 * ZS_STRIDE];
    __shared__ int seg_s[64];
    __shared__ float stat_s[64][2];

    SideP1 S;
    size_t row0;
    if (blockIdx.x < (unsigned)nref_blocks) { S = ref; row0 = (size_t)blockIdx.x * 64; }
    else { S = alt; row0 = (size_t)(blockIdx.x - nref_blocks) * 64; }

    const int tid = threadIdx.x;
    if (tid < 64) {
        int sg = S.seg[row0 + tid];
        seg_s[tid] = sg;
        atomicAdd(&S.seg_cnt[sg], 1.f);   // HW resolves ~2 distinct addrs per wave
    }
    stage_ln1(S.x, row0, tid, n1w, n1b, u);

    const int w = tid >> 6, lane = tid & 63;
    const int lcol = lane & 15, quad = lane >> 4;
    const int mrow = w*16 + lcol;

    short8 a1[4];   // own-wave ys rows -> no barrier needed before these loads
#pragma unroll
    for (int kt = 0; kt < 4; ++kt)
        a1[kt] = *reinterpret_cast<const short8*>(&u[mrow*YS_STRIDE + kt*32 + quad*8]);
    __syncthreads();  // all a1 loaded; ys region may now be overwritten as z2 tile

    float s4[4] = {0,0,0,0}, ss4[4] = {0,0,0,0};
#pragma unroll
    for (int nt = 0; nt < 16; ++nt) {
        int nt_g = 16 + nt;  // z2 columns of F
        f32x4 acc = {0.f,0.f,0.f,0.f};
#pragma unroll
        for (int kt = 0; kt < 4; ++kt) {
            short8 b = *reinterpret_cast<const short8*>(S.w1p + ((size_t)(nt_g*4 + kt)*64 + lane)*8);
            acc = __builtin_amdgcn_mfma_f32_16x16x32_bf16(a1[kt], b, acc, 0, 0, 0);
        }
        int col = nt*16 + lcol;          // H-space column
        float bb = S.b1[256 + col];
#pragma unroll
        for (int reg = 0; reg < 4; ++reg) {
            float z = selu_f(acc[reg] + bb);
            s4[reg] += z; ss4[reg] += z * z;
            u[(w*16 + quad*4 + reg)*ZS_STRIDE + col] = (__bf16)z;
        }
    }
#pragma unroll
    for (int reg = 0; reg < 4; ++reg) {
#pragma unroll
        for (int d = 1; d < 16; d <<= 1) {
            s4[reg]  += __shfl_xor(s4[reg], d);
            ss4[reg] += __shfl_xor(ss4[reg], d);
        }
    }
    if (lcol == 0) {
#pragma unroll
        for (int reg = 0; reg < 4; ++reg) {
            float mean = s4[reg] * (1.f/256.f);
            float var  = ss4[reg] * (1.f/256.f) - mean * mean;
            int row = w*16 + quad*4 + reg;
            stat_s[row][0] = mean;
            stat_s[row][1] = rsqrtf(var + EPS);
        }
    }
    // wave-local: segment sums over this wave's 16 rows; lane <-> column (4 passes)
#pragma unroll
    for (int p = 0; p < 4; ++p) {
        int col = p*64 + lane;
        float nw = n2w[col], nb = n2b[col];
        int scur = seg_s[w*16];
        float run = 0.f;
#pragma unroll
        for (int r16 = 0; r16 < 16; ++r16) {
            int row = w*16 + r16;
            int sg = seg_s[row];
            if (sg != scur) {
                atomicAdd(&S.seg_sum[(size_t)scur * H + col], run);
                run = 0.f; scur = sg;
            }
            run += ((float)u[row*ZS_STRIDE + col] - stat_s[row][0]) * stat_s[row][1] * nw + nb;
        }
        atomicAdd(&S.seg_sum[(size_t)scur * H + col], run);
    }
}

// ---- per-segment gate offsets ----
__global__ void mf_kernel(const float* __restrict__ sum_r, const float* __restrict__ cnt_r,
                          const float* __restrict__ sum_a, const float* __restrict__ cnt_a,
                          const float* __restrict__ regz, const float* __restrict__ reg_w_pre,
                          const float* __restrict__ beta_ref, const float* __restrict__ beta_alt,
                          const float* __restrict__ gamma,
                          float* __restrict__ G_ref, float* __restrict__ G_alt) {
    int s = blockIdx.x, c = threadIdx.x;
    size_t i = (size_t)s * H + c;
    float rw = __expf(reg_w_pre[0]) + 0.25f;
    float mfr = (sum_r[i] + rw * regz[c]) / (cnt_r[s] + rw);
    float mfa = sum_a[i] / fmaxf(cnt_a[s], 1.f);
    G_ref[i] = beta_ref[0] * mfr;
    G_alt[i] = beta_alt[0] * mfa + gamma[0] * mfr;
}

// ---- Pass 2: LN1 -> GEMM1(z2) -> stats -> GEMM1(z1)+gate -> GEMM2 -> +x+b2 ----
__global__ __launch_bounds__(256, 2)
void pass2_kernel(SideP2 ref, SideP2 alt, int nref_blocks,
                  const float* __restrict__ n1w, const float* __restrict__ n1b,
                  const float* __restrict__ n2w, const float* __restrict__ n2b) {
    __shared__ __align__(16) __bf16 u[64 * ZS_STRIDE];
    __shared__ int seg_s[64];
    __shared__ float n2w_s[H], n2b_s[H];

    SideP2 S;
    size_t row0;
    if (blockIdx.x < (unsigned)nref_blocks) { S = ref; row0 = (size_t)blockIdx.x * 64; }
    else { S = alt; row0 = (size_t)(blockIdx.x - nref_blocks) * 64; }

    const int tid = threadIdx.x;
    n2w_s[tid] = n2w[tid]; n2b_s[tid] = n2b[tid];
    if (tid < 64) seg_s[tid] = S.seg[row0 + tid];
    stage_ln1(S.x, row0, tid, n1w, n1b, u);

    const int w = tid >> 6, lane = tid & 63;
    const int lcol = lane & 15, quad = lane >> 4;
    const int mrow = w*16 + lcol;

    short8 a1[4];   // own-wave ys rows
#pragma unroll
    for (int kt = 0; kt < 4; ++kt)
        a1[kt] = *reinterpret_cast<const short8*>(&u[mrow*YS_STRIDE + kt*32 + quad*8]);
    __syncthreads();  // all a1 loaded; u may now be reused as z2/A2 tile

    // z2 half of GEMM1 + SELU + in-register LN2 partials
    float s4[4] = {0,0,0,0}, ss4[4] = {0,0,0,0};
#pragma unroll
    for (int nt = 0; nt < 16; ++nt) {
        int nt_g = 16 + nt;
        f32x4 acc = {0.f,0.f,0.f,0.f};
#pragma unroll
        for (int kt = 0; kt < 4; ++kt) {
            short8 b = *reinterpret_cast<const short8*>(S.w1p + ((size_t)(nt_g*4 + kt)*64 + lane)*8);
            acc = __builtin_amdgcn_mfma_f32_16x16x32_bf16(a1[kt], b, acc, 0, 0, 0);
        }
        int col = nt*16 + lcol;
        float bb = S.b1[256 + col];
#pragma unroll
        for (int reg = 0; reg < 4; ++reg) {
            float z = selu_f(acc[reg] + bb);
            s4[reg] += z; ss4[reg] += z * z;
            u[(w*16 + quad*4 + reg)*ZS_STRIDE + col] = (__bf16)z;
        }
    }
    float mean[4], rsg[4];
#pragma unroll
    for (int reg = 0; reg < 4; ++reg) {
#pragma unroll
        for (int d = 1; d < 16; d <<= 1) {
            s4[reg]  += __shfl_xor(s4[reg], d);
            ss4[reg] += __shfl_xor(ss4[reg], d);
        }
        mean[reg] = s4[reg] * (1.f/256.f);
        float var = ss4[reg] * (1.f/256.f) - mean[reg]*mean[reg];
        rsg[reg] = rsqrtf(var + EPS);
    }

    float alpha = S.alpha[0];
    int segb[4];
#pragma unroll
    for (int reg = 0; reg < 4; ++reg)
        segb[reg] = seg_s[w*16 + quad*4 + reg] * H;

    // z1 half of GEMM1 + SELU + gate; overwrite tile with A2 = z1*gate (same lane/addr)
#pragma unroll
    for (int nt = 0; nt < 16; ++nt) {
        f32x4 acc = {0.f,0.f,0.f,0.f};
#pragma unroll
        for (int kt = 0; kt < 4; ++kt) {
            short8 b = *reinterpret_cast<const short8*>(S.w1p + ((size_t)(nt*4 + kt)*64 + lane)*8);
            acc = __builtin_amdgcn_mfma_f32_16x16x32_bf16(a1[kt], b, acc, 0, 0, 0);
        }
        int col = nt*16 + lcol;
        float bb = S.b1[col];
        float nw = n2w_s[col], nb = n2b_s[col];
#pragma unroll
        for (int reg = 0; reg < 4; ++reg) {
            int row = w*16 + quad*4 + reg;
            float z1 = selu_f(acc[reg] + bb);
            float z2 = (float)u[row*ZS_STRIDE + col];
            float z2n = (z2 - mean[reg]) * rsg[reg] * nw + nb;
            float gate = z2n * alpha + 1.f + S.G[segb[reg] + col];
            u[row*ZS_STRIDE + col] = (__bf16)(z1 * gate);
        }
    }

    // GEMM2: (64x256)@(256x128) + b2 -> C staged in LDS (f32, own-wave rows)
    short8 a2[8];
#pragma unroll
    for (int kt = 0; kt < 8; ++kt)
        a2[kt] = *reinterpret_cast<const short8*>(&u[mrow*ZS_STRIDE + kt*32 + quad*8]);
    float* cf = reinterpret_cast<float*>(u);
#pragma unroll
    for (int nt = 0; nt < 8; ++nt) {
        f32x4 acc = {0.f,0.f,0.f,0.f};
#pragma unroll
        for (int kt = 0; kt < 8; ++kt) {
            short8 b = *reinterpret_cast<const short8*>(S.w2p + ((size_t)(nt*8 + kt)*64 + lane)*8);
            acc = __builtin_amdgcn_mfma_f32_16x16x32_bf16(a2[kt], b, acc, 0, 0, 0);
        }
        int col = nt*16 + lcol;
        float bb = S.b2[col];
#pragma unroll
        for (int reg = 0; reg < 4; ++reg)
            cf[(w*16 + quad*4 + reg)*CS_STRIDE + col] = acc[reg] + bb;
    }
    __syncthreads();

    // fully-coalesced residual add + store: wave writes 4KB contiguous per instr
#pragma unroll
    for (int i = 0; i < 8; ++i) {
        int idx = i*1024 + tid*4;
        int r = idx >> 7, c = idx & 127;
        float4 res = *reinterpret_cast<const float4*>(S.x + row0*D + idx);
        float4 o;
        o.x = cf[r*CS_STRIDE + c + 0] + res.x;
        o.y = cf[r*CS_STRIDE + c + 1] + res.y;
        o.z = cf[r*CS_STRIDE + c + 2] + res.z;
        o.w = cf[r*CS_STRIDE + c + 3] + res.w;
        *reinterpret_cast<float4*>(S.out + row0*D + idx) = o;
    }
}

extern "C" void kernel_launch(void* const* d_in, const int* in_sizes, int n_in,
                              void* d_out, int out_size, void* d_ws, size_t ws_size,
                              hipStream_t stream) {
    const float* ref_flat = (const float*)d_in[0];
    const float* alt_flat = (const float*)d_in[1];
    const int*   ref_seg  = (const int*)d_in[2];
    const int*   alt_seg  = (const int*)d_in[3];
    const float* norm1_w  = (const float*)d_in[4];
    const float* norm1_b  = (const float*)d_in[5];
    const float* w1_ref   = (const float*)d_in[6];
    const float* b1_ref   = (const float*)d_in[7];
    const float* w1_alt   = (const float*)d_in[8];
    const float* b1_alt   = (const float*)d_in[9];
    const float* norm2_w  = (const float*)d_in[10];
    const float* norm2_b  = (const float*)d_in[11];
    const float* alpha_ref = (const float*)d_in[12];
    const float* alpha_alt = (const float*)d_in[13];
    const float* beta_ref  = (const float*)d_in[14];
    const float* beta_alt  = (const float*)d_in[15];
    const float* gamma     = (const float*)d_in[16];
    const float* ref_regularizer = (const float*)d_in[17];
    const float* reg_w_pre = (const float*)d_in[18];
    const float* w2_ref   = (const float*)d_in[19];
    const float* b2_ref   = (const float*)d_in[20];
    const float* w2_alt   = (const float*)d_in[21];
    const float* b2_alt   = (const float*)d_in[22];

    char* ws = (char*)d_ws;
    float* sum_r = (float*)(ws);                      // 4 MB
    float* sum_a = (float*)(ws + 4194304);            // 4 MB
    float* cnt_r = (float*)(ws + 8388608);            // 16 KB
    float* cnt_a = (float*)(ws + 8404992);            // 16 KB
    float* G_ref = (float*)(ws + 8421376);            // 4 MB
    float* G_alt = (float*)(ws + 12615680);           // 4 MB
    __bf16* w1p_r = (__bf16*)(ws + 16809984);         // 128 KB
    __bf16* w1p_a = (__bf16*)(ws + 16941056);         // 128 KB
    __bf16* w2p_r = (__bf16*)(ws + 17072128);         // 64 KB
    __bf16* w2p_a = (__bf16*)(ws + 17137664);         // 64 KB

    hipMemsetAsync(d_ws, 0, 8421376, stream);  // zero sums + counts (atomic targets)

    pack_all<<<768, 256, 0, stream>>>(w1_ref, w1_alt, w2_ref, w2_alt, w1p_r, w1p_a, w2p_r, w2p_a);

    SideP1 p1r = { ref_flat, ref_seg, w1p_r, b1_ref, sum_r, cnt_r };
    SideP1 p1a = { alt_flat, alt_seg, w1p_a, b1_alt, sum_a, cnt_a };
    pass1_kernel<<<NREF/64 + NALT/64, 256, 0, stream>>>(p1r, p1a, NREF/64,
                                                        norm1_w, norm1_b, norm2_w, norm2_b);

    mf_kernel<<<BSEG, 256, 0, stream>>>(sum_r, cnt_r, sum_a, cnt_a, ref_regularizer, reg_w_pre,
                                        beta_ref, beta_alt, gamma, G_ref, G_alt);

    SideP2 p2r = { ref_flat, ref_seg, w1p_r, b1_ref, w2p_r, b2_ref, alpha_ref, G_ref,
                   (float*)d_out };
    SideP2 p2a = { alt_flat, alt_seg, w1p_a, b1_alt, w2p_a, b2_alt, alpha_alt, G_alt,
                   (float*)d_out + (size_t)NREF * D };
    pass2_kernel<<<NREF/64 + NALT/64, 256, 0, stream>>>(p2r, p2a, NREF/64,
                                                        norm1_w, norm1_b, norm2_w, norm2_b);
}